// Round 1
// baseline (743.790 us; speedup 1.0000x reference)
//
#include <hip/hip_runtime.h>
#include <math.h>

#define DIM 128
#define HID 512
#define BATCHN 16384
#define NSTEPS 20
#define ROWSTRIDE 131                 // DIM + 3 aug columns
#define SLICE (BATCHN * ROWSTRIDE)    // floats per trajectory step
#define BM 64                         // batch rows per block
#define HCST 520                      // hc row stride (bf16), 16B-aligned
#define YBST 136                      // ybf row stride (bf16), 16B-aligned

typedef __bf16 bf16_t;
typedef __bf16 bf16x8 __attribute__((ext_vector_type(8)));
typedef float floatx4 __attribute__((ext_vector_type(4)));

__device__ __forceinline__ float fast_tanh(float x) {
    float e = __expf(2.0f * x);
    return 1.0f - 2.0f / (e + 1.0f);
}

// ws layout: W1T bf16 [512][128] @0 ; W2T bf16 [128][512] @131072 ;
//            biasEff f32 [20][512] @262144
__global__ void prep_kernel(const float* __restrict__ W1, const float* __restrict__ b1,
                            const float* __restrict__ W2, const float* __restrict__ ts,
                            bf16_t* __restrict__ W1T, bf16_t* __restrict__ W2T,
                            float* __restrict__ biasEff) {
    int tid = blockIdx.x * blockDim.x + threadIdx.x;   // 0..65535
    {   int j = tid >> 7, k = tid & 127;               // W1T[j][k] = W1[k][j]
        W1T[j * DIM + k] = (bf16_t)W1[k * HID + j]; }
    {   int j = tid >> 9, k = tid & 511;               // W2T[j][k] = W2[k][j]
        W2T[j * HID + k] = (bf16_t)W2[k * DIM + j]; }
    if (tid < NSTEPS * HID) {                          // b1[j] + ts[s]*W1[128][j]
        int s = tid >> 9, j = tid & 511;
        biasEff[tid] = b1[j] + ts[s] * W1[DIM * HID + j];
    }
}

// Persistent fused kernel: one block owns BM=64 rows for all 20 steps.
// 8 waves/block. Wave w: GEMM1 hidden slice [w*64, w*64+64) (1M x 8N grid);
// GEMM2 output cols [w*16, w*16+16) with full K=512 (W2 frags in VGPRs).
// y state: f32 in registers (epilogue layout) + bf16 copy in LDS for A-frags.
// LDS: ybf bf16[64][136] @0 (17408) ; hc bf16[64][520] @17408 (66560)
//      red f32[64][8][2] @83968 (4096) ; augL f32[64][4] @88064 (1024)
// Two barriers per step. Zero weight traffic in-loop except W1 (L2, 128KB/step).
__global__ __launch_bounds__(512, 2)
void fused_kernel(const float* __restrict__ y0, float* __restrict__ traj,
                  const float* __restrict__ noises,
                  const bf16_t* __restrict__ W1T, const bf16_t* __restrict__ W2T,
                  const float* __restrict__ biasEff, const float* __restrict__ b2,
                  const float* __restrict__ ts) {
    __shared__ __align__(16) char smem[89088];
    bf16_t* ybf  = (bf16_t*)smem;
    bf16_t* hc   = (bf16_t*)(smem + 17408);
    float*  red  = (float*)(smem + 83968);
    float*  augL = (float*)(smem + 88064);

    const int tid  = threadIdx.x;
    const int lane = tid & 63;
    const int w    = tid >> 6;      // wave 0..7
    const int quad = lane >> 4;
    const int l15  = lane & 15;
    const int row0 = blockIdx.x * BM;
    const int col  = w * 16 + l15;  // this lane's output column (GEMM2/epilogue)

    // ---- persistent W2 fragments: 16 x bf16x8 = 64 VGPRs, loaded once ----
    bf16x8 w2f[16];
    {
        const bf16_t* W2r = W2T + (size_t)col * HID + quad * 8;
        #pragma unroll
        for (int k0 = 0; k0 < 16; ++k0)
            w2f[k0] = *(const bf16x8*)(W2r + k0 * 32);
    }
    const float b2c = b2[col];

    // ---- init: y0 -> registers + ybf LDS + trajectory slice 0 ----
    float yv[4][4];
    {
        const float* y0b = y0 + (size_t)row0 * DIM;
        #pragma unroll
        for (int m = 0; m < 4; ++m)
            #pragma unroll
            for (int i = 0; i < 4; ++i) {
                int r = m * 16 + quad * 4 + i;
                float v = y0b[(size_t)r * DIM + col];
                yv[m][i] = v;
                traj[(size_t)(row0 + r) * ROWSTRIDE + col] = v;
                ybf[r * YBST + col] = (bf16_t)v;
            }
        if (tid < BM) {
            float* ag = augL + tid * 4;
            ag[0] = 0.f; ag[2] = 0.f;
            float* o = traj + (size_t)(row0 + tid) * ROWSTRIDE + DIM;
            o[0] = 0.f; o[1] = 0.f; o[2] = 0.f;
        }
        if (blockIdx.x == 0 && tid <= NSTEPS)
            traj[(size_t)(NSTEPS + 1) * SLICE + tid] = ts[tid];
    }
    __syncthreads();

    #pragma unroll 1
    for (int s = 0; s < NSTEPS; ++s) {
        const float tdt = ts[s + 1] - ts[s];
        const float sq  = sqrtf(tdt);

        // ---- prefetch this step's noise (consumed ~2 GEMMs later) ----
        float nz[4][4];
        {
            const float* nb = noises + (size_t)s * (BATCHN * DIM) + (size_t)row0 * DIM;
            #pragma unroll
            for (int m = 0; m < 4; ++m)
                #pragma unroll
                for (int i = 0; i < 4; ++i)
                    nz[m][i] = nb[(size_t)(m * 16 + quad * 4 + i) * DIM + col];
        }
        float bias[4];
        {
            const float* be = biasEff + s * HID + w * 64;
            #pragma unroll
            for (int jn = 0; jn < 4; ++jn) bias[jn] = be[jn * 16 + l15];
        }

        // ---- A fragments from ybf (y of previous step) ----
        bf16x8 a1[4][4];
        #pragma unroll
        for (int m = 0; m < 4; ++m)
            #pragma unroll
            for (int k0 = 0; k0 < 4; ++k0)
                a1[m][k0] = *(const bf16x8*)(ybf + (m * 16 + l15) * YBST + k0 * 32 + quad * 8);

        // ---- GEMM1 (64 rows x 64 hidden per wave, K=128) + tanh -> hc ----
        const bf16_t* W1w = W1T + (size_t)(w * 64) * DIM;
        #pragma unroll
        for (int jn = 0; jn < 4; ++jn) {
            floatx4 acc1[4];
            acc1[0] = acc1[1] = acc1[2] = acc1[3] = (floatx4){0.f, 0.f, 0.f, 0.f};
            #pragma unroll
            for (int k0 = 0; k0 < 4; ++k0) {
                bf16x8 bv = *(const bf16x8*)(W1w + (jn * 16 + l15) * DIM + k0 * 32 + quad * 8);
                #pragma unroll
                for (int m = 0; m < 4; ++m)
                    acc1[m] = __builtin_amdgcn_mfma_f32_16x16x32_bf16(a1[m][k0], bv, acc1[m], 0, 0, 0);
            }
            #pragma unroll
            for (int m = 0; m < 4; ++m)
                #pragma unroll
                for (int i = 0; i < 4; ++i)
                    hc[(m * 16 + quad * 4 + i) * HCST + w * 64 + jn * 16 + l15] =
                        (bf16_t)fast_tanh(acc1[m][i] + bias[jn]);
        }
        __syncthreads();   // B1: hc visible; also orders prev combine vs red rewrite

        // ---- GEMM2: 64 rows x 16 cols per wave, full K=512, W2 in regs ----
        floatx4 accu[4];
        accu[0] = accu[1] = accu[2] = accu[3] = (floatx4){0.f, 0.f, 0.f, 0.f};
        #pragma unroll
        for (int k0 = 0; k0 < 16; ++k0) {
            #pragma unroll
            for (int m = 0; m < 4; ++m) {
                bf16x8 a2 = *(const bf16x8*)(hc + (m * 16 + l15) * HCST + k0 * 32 + quad * 8);
                accu[m] = __builtin_amdgcn_mfma_f32_16x16x32_bf16(a2, w2f[k0], accu[m], 0, 0, 0);
            }
        }

        // ---- epilogue: SDE update straight from accumulators ----
        float* trajN = traj + (size_t)(s + 1) * SLICE;
        float udwp[4][4], enp[4][4];
        #pragma unroll
        for (int m = 0; m < 4; ++m)
            #pragma unroll
            for (int i = 0; i < 4; ++i) {
                int r = m * 16 + quad * 4 + i;
                float u  = accu[m][i] + b2c;
                float y  = yv[m][i];
                float yn = y + (u - y) * tdt + sq * nz[m][i];   // ALPHA=SIGMA=1
                yv[m][i] = yn;
                trajN[(size_t)(row0 + r) * ROWSTRIDE + col] = yn;
                ybf[r * YBST + col] = (bf16_t)yn;
                udwp[m][i] = u * nz[m][i];
                enp[m][i]  = u * u;
            }
        // reduce each (m,i) over the 16 cols of this wave (xor within quad-16 group)
        #pragma unroll
        for (int m = 0; m < 4; ++m)
            #pragma unroll
            for (int i = 0; i < 4; ++i) {
                float a = udwp[m][i], b = enp[m][i];
                a += __shfl_xor(a, 1);  b += __shfl_xor(b, 1);
                a += __shfl_xor(a, 2);  b += __shfl_xor(b, 2);
                a += __shfl_xor(a, 4);  b += __shfl_xor(b, 4);
                a += __shfl_xor(a, 8);  b += __shfl_xor(b, 8);
                udwp[m][i] = a; enp[m][i] = b;
            }
        if (l15 == 0) {   // static-indexed writes (no runtime reg indexing)
            #pragma unroll
            for (int m = 0; m < 4; ++m)
                #pragma unroll
                for (int i = 0; i < 4; ++i) {
                    int r = m * 16 + quad * 4 + i;
                    float* rp = red + (r * 8 + w) * 2;
                    rp[0] = udwp[m][i];
                    rp[1] = enp[m][i];
                }
        }
        __syncthreads();   // B2: ybf + red visible

        // ---- combine 8 col-wave partials, update aug accumulators ----
        if (tid < BM) {
            const float* rp = red + tid * 16;
            float du = 0.f, en = 0.f;
            #pragma unroll
            for (int k = 0; k < 8; ++k) { du += rp[k * 2]; en += rp[k * 2 + 1]; }
            float* ag = augL + tid * 4;
            float a0  = ag[0] + du * sq;
            float a2v = ag[2] + 0.5f * en * tdt;
            ag[0] = a0; ag[2] = a2v;
            float* o = trajN + (size_t)(row0 + tid) * ROWSTRIDE + DIM;
            o[0] = a0; o[1] = a0; o[2] = a2v;   // udw == udw_det numerically
        }
    }
}

extern "C" void kernel_launch(void* const* d_in, const int* in_sizes, int n_in,
                              void* d_out, int out_size, void* d_ws, size_t ws_size,
                              hipStream_t stream) {
    const float* y0     = (const float*)d_in[0];
    const float* W1     = (const float*)d_in[1];
    const float* b1     = (const float*)d_in[2];
    const float* W2     = (const float*)d_in[3];
    const float* b2     = (const float*)d_in[4];
    const float* noises = (const float*)d_in[5];
    const float* ts     = (const float*)d_in[6];
    float* out = (float*)d_out;

    bf16_t* W1T     = (bf16_t*)d_ws;
    bf16_t* W2T     = (bf16_t*)((char*)d_ws + 131072);
    float*  biasEff = (float*)((char*)d_ws + 262144);

    prep_kernel<<<256, 256, 0, stream>>>(W1, b1, W2, ts, W1T, W2T, biasEff);
    fused_kernel<<<BATCHN / BM, 512, 0, stream>>>(y0, out, noises, W1T, W2T,
                                                  biasEff, b2, ts);
}

// Round 2
// 490.645 us; speedup vs baseline: 1.5159x; 1.5159x over previous
//
#include <hip/hip_runtime.h>
#include <math.h>

#define DIM 128
#define HID 512
#define BATCHN 16384
#define NSTEPS 20
#define ROWSTRIDE 131                 // DIM + 3 aug columns
#define SLICE (BATCHN * ROWSTRIDE)    // floats per trajectory step
#define BM 32                         // batch rows per block
#define HCST 520                      // hc row stride (bf16)
#define YBST 136                      // ybf row stride (bf16)
#define REDST 18                      // red row stride (f32), odd-ish to spread banks

typedef __bf16 bf16_t;
typedef __bf16 bf16x8 __attribute__((ext_vector_type(8)));
typedef float floatx4 __attribute__((ext_vector_type(4)));

__device__ __forceinline__ float fast_tanh(float x) {
    float e = __expf(2.0f * x);
    return 1.0f - 2.0f / (e + 1.0f);
}

// ws layout: W1T bf16 [512][128] @0 ; W2T bf16 [128][512] @131072 ;
//            biasEff f32 [20][512] @262144
__global__ void prep_kernel(const float* __restrict__ W1, const float* __restrict__ b1,
                            const float* __restrict__ W2, const float* __restrict__ ts,
                            bf16_t* __restrict__ W1T, bf16_t* __restrict__ W2T,
                            float* __restrict__ biasEff) {
    int tid = blockIdx.x * blockDim.x + threadIdx.x;   // 0..65535
    {   int j = tid >> 7, k = tid & 127;               // W1T[j][k] = W1[k][j]
        W1T[j * DIM + k] = (bf16_t)W1[k * HID + j]; }
    {   int j = tid >> 9, k = tid & 511;               // W2T[j][k] = W2[k][j]
        W2T[j * HID + k] = (bf16_t)W2[k * DIM + j]; }
    if (tid < NSTEPS * HID) {                          // b1[j] + ts[s]*W1[128][j]
        int s = tid >> 9, j = tid & 511;
        biasEff[tid] = b1[j] + ts[s] * W1[DIM * HID + j];
    }
}

// Persistent fused kernel, v3.
// 512 blocks x 512 threads (8 waves), BM=32 rows/block, 20 steps in-kernel.
// Wave w: GEMM1 hidden slice [w*64, w*64+64) with W1 frags in VGPRs (64);
//         GEMM2 output cols [w*16, w*16+16), full K=512, W2 frags in VGPRs (64).
// y state: f32 regs (MFMA C layout). Zero in-loop weight traffic.
// Output staged in LDS outImg [32][131] f32, streamed as 131 aligned 128B lines
// per block (region = blockIdx*16768B, exactly line-aligned) -> no RMW.
// LDS: ybf bf16[32][136] @0 (8704) ; hc bf16[32][520] @8704 (33280)
//      outImg f32[32][131] @41984 (16768) ; red f32[32][18] @58752 (2304)
// 3 barriers/step: B1 post-GEMM1(hc), B2 post-epilogue(red/outImg-y),
// B3 post-aug-combine (outImg complete) -> stream.
__global__ __launch_bounds__(512, 2)
void fused_kernel(const float* __restrict__ y0, float* __restrict__ traj,
                  const float* __restrict__ noises,
                  const bf16_t* __restrict__ W1T, const bf16_t* __restrict__ W2T,
                  const float* __restrict__ biasEff, const float* __restrict__ b2,
                  const float* __restrict__ ts) {
    __shared__ __align__(16) char smem[61056];
    bf16_t* ybf    = (bf16_t*)smem;
    bf16_t* hc     = (bf16_t*)(smem + 8704);
    float*  outImg = (float*)(smem + 41984);
    float*  red    = (float*)(smem + 58752);

    const int tid  = threadIdx.x;
    const int lane = tid & 63;
    const int w    = tid >> 6;      // wave 0..7
    const int quad = lane >> 4;
    const int l15  = lane & 15;
    const int row0 = blockIdx.x * BM;
    const int col  = w * 16 + l15;  // this lane's output column (GEMM2/epilogue)

    // ---- persistent weight fragments (loaded once) ----
    bf16x8 w1f[4][4];               // wave's 64 hidden rows x K=128
    {
        const bf16_t* W1w = W1T + (size_t)(w * 64) * DIM;
        #pragma unroll
        for (int jn = 0; jn < 4; ++jn)
            #pragma unroll
            for (int k0 = 0; k0 < 4; ++k0)
                w1f[jn][k0] = *(const bf16x8*)(W1w + (jn * 16 + l15) * DIM + k0 * 32 + quad * 8);
    }
    bf16x8 w2f[16];                 // lane's output col x K=512
    {
        const bf16_t* W2r = W2T + (size_t)col * HID + quad * 8;
        #pragma unroll
        for (int k0 = 0; k0 < 16; ++k0)
            w2f[k0] = *(const bf16x8*)(W2r + k0 * 32);
    }
    const float b2c = b2[col];

    // ---- init: y0 -> regs (MFMA layout) + ybf + outImg; stream slice 0 ----
    float yv[2][4];
    {
        const float* y0b = y0 + (size_t)row0 * DIM;
        #pragma unroll
        for (int m = 0; m < 2; ++m)
            #pragma unroll
            for (int i = 0; i < 4; ++i) {
                int r = m * 16 + quad * 4 + i;
                float v = y0b[(size_t)r * DIM + col];
                yv[m][i] = v;
                outImg[r * ROWSTRIDE + col] = v;
                ybf[r * YBST + col] = (bf16_t)v;
            }
    }
    float aug0 = 0.f, aug2 = 0.f;   // per-row aug state (valid in tid<32 lanes)
    if (tid < BM) {
        float* o = outImg + tid * ROWSTRIDE + DIM;
        o[0] = 0.f; o[1] = 0.f; o[2] = 0.f;
    }
    if (blockIdx.x == 0 && tid <= NSTEPS)
        traj[(size_t)(NSTEPS + 1) * SLICE + tid] = ts[tid];
    __syncthreads();
    {
        float* dst = traj + (size_t)row0 * ROWSTRIDE;
        const floatx4* srcv = (const floatx4*)outImg;
        for (int i2 = tid; i2 < (BM * ROWSTRIDE) / 4; i2 += 512)
            ((floatx4*)dst)[i2] = srcv[i2];
    }

    #pragma unroll 1
    for (int s = 0; s < NSTEPS; ++s) {
        const float dt = ts[s + 1] - ts[s];
        const float sq = sqrtf(dt);

        // ---- prefetch noise (sector-aligned 64B reads) + bias ----
        float nz[2][4];
        {
            const float* nb = noises + (size_t)s * (BATCHN * DIM) + (size_t)row0 * DIM;
            #pragma unroll
            for (int m = 0; m < 2; ++m)
                #pragma unroll
                for (int i = 0; i < 4; ++i)
                    nz[m][i] = nb[(size_t)(m * 16 + quad * 4 + i) * DIM + col];
        }
        float bias[4];
        {
            const float* be = biasEff + s * HID + w * 64;
            #pragma unroll
            for (int jn = 0; jn < 4; ++jn) bias[jn] = be[jn * 16 + l15];
        }

        // ---- A fragments (y of previous step, bf16) ----
        bf16x8 a1[2][4];
        #pragma unroll
        for (int m = 0; m < 2; ++m)
            #pragma unroll
            for (int k0 = 0; k0 < 4; ++k0)
                a1[m][k0] = *(const bf16x8*)(ybf + (m * 16 + l15) * YBST + k0 * 32 + quad * 8);

        // ---- GEMM1 (32 rows x 64 hidden per wave, K=128, weights in regs) ----
        #pragma unroll
        for (int jn = 0; jn < 4; ++jn) {
            floatx4 acc1[2];
            acc1[0] = (floatx4){0.f, 0.f, 0.f, 0.f};
            acc1[1] = (floatx4){0.f, 0.f, 0.f, 0.f};
            #pragma unroll
            for (int k0 = 0; k0 < 4; ++k0) {
                acc1[0] = __builtin_amdgcn_mfma_f32_16x16x32_bf16(a1[0][k0], w1f[jn][k0], acc1[0], 0, 0, 0);
                acc1[1] = __builtin_amdgcn_mfma_f32_16x16x32_bf16(a1[1][k0], w1f[jn][k0], acc1[1], 0, 0, 0);
            }
            #pragma unroll
            for (int m = 0; m < 2; ++m)
                #pragma unroll
                for (int i = 0; i < 4; ++i)
                    hc[(m * 16 + quad * 4 + i) * HCST + w * 64 + jn * 16 + l15] =
                        (bf16_t)fast_tanh(acc1[m][i] + bias[jn]);
        }
        __syncthreads();   // B1: hc complete (also: all ybf reads done)

        // ---- GEMM2: 32 rows x 16 cols per wave, full K=512, W2 in regs ----
        floatx4 accu[2];
        accu[0] = (floatx4){0.f, 0.f, 0.f, 0.f};
        accu[1] = (floatx4){0.f, 0.f, 0.f, 0.f};
        #pragma unroll
        for (int k0 = 0; k0 < 16; ++k0) {
            bf16x8 a20 = *(const bf16x8*)(hc + l15 * HCST + k0 * 32 + quad * 8);
            bf16x8 a21 = *(const bf16x8*)(hc + (16 + l15) * HCST + k0 * 32 + quad * 8);
            accu[0] = __builtin_amdgcn_mfma_f32_16x16x32_bf16(a20, w2f[k0], accu[0], 0, 0, 0);
            accu[1] = __builtin_amdgcn_mfma_f32_16x16x32_bf16(a21, w2f[k0], accu[1], 0, 0, 0);
        }

        // ---- epilogue: SDE update from accumulators into LDS out-image ----
        #pragma unroll
        for (int m = 0; m < 2; ++m)
            #pragma unroll
            for (int i = 0; i < 4; ++i) {
                int r = m * 16 + quad * 4 + i;
                float u  = accu[m][i] + b2c;
                float y  = yv[m][i];
                float yn = y + (u - y) * dt + sq * nz[m][i];   // ALPHA=SIGMA=1
                yv[m][i] = yn;
                outImg[r * ROWSTRIDE + col] = yn;
                ybf[r * YBST + col] = (bf16_t)yn;
                float pdu = u * nz[m][i];
                float pen = u * u;
                pdu += __shfl_xor(pdu, 1); pen += __shfl_xor(pen, 1);
                pdu += __shfl_xor(pdu, 2); pen += __shfl_xor(pen, 2);
                pdu += __shfl_xor(pdu, 4); pen += __shfl_xor(pen, 4);
                pdu += __shfl_xor(pdu, 8); pen += __shfl_xor(pen, 8);
                if (l15 == 0) {
                    red[r * REDST + w * 2]     = pdu;
                    red[r * REDST + w * 2 + 1] = pen;
                }
            }
        __syncthreads();   // B2: red + outImg y-part + ybf complete

        // ---- combine 8 col-wave partials, update aug, finish out-image ----
        if (tid < BM) {
            const float* rp = red + tid * REDST;
            float du = 0.f, en = 0.f;
            #pragma unroll
            for (int k = 0; k < 8; ++k) { du += rp[k * 2]; en += rp[k * 2 + 1]; }
            aug0 += du * sq;
            aug2 += 0.5f * en * dt;
            float* o = outImg + tid * ROWSTRIDE + DIM;
            o[0] = aug0; o[1] = aug0; o[2] = aug2;   // udw == udw_det numerically
        }
        __syncthreads();   // B3: outImg complete

        // ---- stream out: 131 aligned 128B lines per block, zero RMW ----
        {
            float* dst = traj + (size_t)(s + 1) * SLICE + (size_t)row0 * ROWSTRIDE;
            const floatx4* srcv = (const floatx4*)outImg;
            for (int i2 = tid; i2 < (BM * ROWSTRIDE) / 4; i2 += 512)
                ((floatx4*)dst)[i2] = srcv[i2];
        }
    }
}

extern "C" void kernel_launch(void* const* d_in, const int* in_sizes, int n_in,
                              void* d_out, int out_size, void* d_ws, size_t ws_size,
                              hipStream_t stream) {
    const float* y0     = (const float*)d_in[0];
    const float* W1     = (const float*)d_in[1];
    const float* b1     = (const float*)d_in[2];
    const float* W2     = (const float*)d_in[3];
    const float* b2     = (const float*)d_in[4];
    const float* noises = (const float*)d_in[5];
    const float* ts     = (const float*)d_in[6];
    float* out = (float*)d_out;

    bf16_t* W1T     = (bf16_t*)d_ws;
    bf16_t* W2T     = (bf16_t*)((char*)d_ws + 131072);
    float*  biasEff = (float*)((char*)d_ws + 262144);

    prep_kernel<<<256, 256, 0, stream>>>(W1, b1, W2, ts, W1T, W2T, biasEff);
    fused_kernel<<<BATCHN / BM, 512, 0, stream>>>(y0, out, noises, W1T, W2T,
                                                  biasEff, b2, ts);
}